// Round 1
// baseline (1021.171 us; speedup 1.0000x reference)
//
#include <hip/hip_runtime.h>
#include <stdint.h>
#include <math.h>

typedef __bf16 bf16;
typedef __attribute__((ext_vector_type(8))) __bf16 bf16x8;
typedef __attribute__((ext_vector_type(16))) float f32x16;

#define AS1 __attribute__((address_space(1)))
#define AS3 __attribute__((address_space(3)))

__device__ __forceinline__ void glds16(const void* g, void* l) {
    __builtin_amdgcn_global_load_lds((const AS1 uint32_t*)g, (AS3 uint32_t*)l, 16, 0, 0);
}

// Fragment-tile (FT) layout for X[M,K]: tile (rb=r>>5, ks=k>>4) is 512 elems:
// addr = (rb*(K/16)+ks)*512 + (((k>>3)&1)*32 + (r&31))*8 + (k&7).
// A wave's MFMA fragment = 1KB contiguous -> coalesced staging loads, 0 LDS
// bank conflicts (linear copy; read addr == write order).

// ---------- setup: A_gcn (gmat[0..15]) and M_sage (gmat[16..31]) -----------
__global__ void k_setup(const int* __restrict__ ei, float* __restrict__ gmat) {
    if (threadIdx.x != 0 || blockIdx.x != 0) return;
    bool is64 = true;
    for (int i = 0; i < 12; i++) if (ei[2 * i + 1] != 0) { is64 = false; break; }
    int src[12], dst[12];
    for (int e = 0; e < 12; e++) {
        if (is64) { src[e] = ei[2 * e]; dst[e] = ei[24 + 2 * e]; }
        else      { src[e] = ei[e];     dst[e] = ei[12 + e]; }
    }
    float deg[4] = {1.f, 1.f, 1.f, 1.f};
    for (int e = 0; e < 12; e++) deg[dst[e]] += 1.f;
    float dinv[4];
    for (int n = 0; n < 4; n++) dinv[n] = 1.f / sqrtf(deg[n]);
    float A[16];
    for (int i = 0; i < 16; i++) A[i] = 0.f;
    for (int e = 0; e < 12; e++) A[dst[e] * 4 + src[e]] += dinv[src[e]] * dinv[dst[e]];
    for (int n = 0; n < 4; n++) A[n * 4 + n] += dinv[n] * dinv[n];
    float cnt[4] = {0.f, 0.f, 0.f, 0.f};
    for (int e = 0; e < 12; e++) cnt[dst[e]] += 1.f;
    for (int n = 0; n < 4; n++) cnt[n] = fmaxf(cnt[n], 1.f);
    float Mm[16];
    for (int i = 0; i < 16; i++) Mm[i] = 0.f;
    for (int e = 0; e < 12; e++) Mm[dst[e] * 4 + src[e]] += 1.f;
    for (int n = 0; n < 4; n++)
        for (int m = 0; m < 4; m++) Mm[n * 4 + m] /= cnt[n];
    for (int i = 0; i < 16; i++) { gmat[i] = A[i]; gmat[16 + i] = Mm[i]; }
}

// ---------- W [K,N] -> Wt FT[N,K] bf16 -------------------------------------
__global__ __launch_bounds__(256) void wtransF(const float* __restrict__ W, int K,
                                               int N, bf16* __restrict__ Wt) {
    int a = blockIdx.x * 256 + threadIdx.x;
    if (a >= N * K) return;
    int j = a & 7, c64 = (a >> 3) & 63, tile = a >> 9;
    int m32 = c64 & 31, kh = c64 >> 5;
    int TK = K >> 4;
    int rblk = tile / TK, ks = tile - rblk * TK;
    int n = rblk * 32 + m32, k = ks * 16 + kh * 8 + j;
    Wt[a] = (bf16)W[(size_t)k * N + n];
}

// ---------- interleaved [Wl|Wr] -> Wt FT[2F,K]; row 2f->Wl, 2f+1->Wr -------
__global__ __launch_bounds__(256) void wtransI(const float* __restrict__ Wl,
                                               const float* __restrict__ Wr,
                                               int K, int F, bf16* __restrict__ Bt) {
    int a = blockIdx.x * 256 + threadIdx.x;
    if (a >= 2 * F * K) return;
    int j = a & 7, c64 = (a >> 3) & 63, tile = a >> 9;
    int m32 = c64 & 31, kh = c64 >> 5;
    int TK = K >> 4;
    int rblk = tile / TK, ks = tile - rblk * TK;
    int n = rblk * 32 + m32, k = ks * 16 + kh * 8 + j;
    int f = n >> 1;
    float v = (n & 1) ? Wr[(size_t)k * F + f] : Wl[(size_t)k * F + f];
    Bt[a] = (bf16)v;
}

// ---------- cast fp32 x [M,64] -> bf16 FT ----------------------------------
__global__ __launch_bounds__(256) void cast_x(const float4* __restrict__ x,
                                              bf16x8* __restrict__ out) {
    int i = blockIdx.x * 256 + threadIdx.x;   // chunk index over M*8
    int c64 = i & 63, m32 = c64 & 31, kh = c64 >> 5;
    int tile = i >> 6, RB = tile >> 2, ks = tile & 3;
    int row = RB * 32 + m32;
    int fb4 = ks * 4 + kh * 2;                // float4 index within 16/row
    float4 a = x[(size_t)row * 16 + fb4], b = x[(size_t)row * 16 + fb4 + 1];
    bf16x8 o;
    o[0] = (bf16)a.x; o[1] = (bf16)a.y; o[2] = (bf16)a.z; o[3] = (bf16)a.w;
    o[4] = (bf16)b.x; o[5] = (bf16)b.y; o[6] = (bf16)b.z; o[7] = (bf16)b.w;
    out[i] = o;
}

// ---------- zero ssq accumulators ------------------------------------------
__global__ __launch_bounds__(256) void k_zero(float4* __restrict__ p, int n4) {
    int i = blockIdx.x * 256 + threadIdx.x;
    if (i < n4) p[i] = make_float4(0.f, 0.f, 0.f, 0.f);
}

// ---------- MFMA GEMM, 256x256 tile, BK=64, 8 waves, 8-phase counted-vmcnt -
// T3+T4+T5 schedule (guide §5.5): double-buffered LDS (128 KiB), 4 phases per
// K-tile, each phase = {vmcnt(6); s_barrier; 6x ds_read_b128; 2x glds16
// next-tile prefetch; setprio(1); 8x mfma_32x32x16; setprio(0)}. vmcnt(6)
// retires exactly the oldest staging issue (= this phase's slots); loads stay
// in flight across barriers (never vmcnt(0) in the loop). FT layout keeps
// LDS linear + conflict-free (T2 equivalent). Last tile wrap-stages the
// current (L2-hot) tile so counts stay uniform; single drain before epilogue.
// mode 1 (GCN): out = FT(mix4(A@Bt^T)+bias, ReLU) with next-K = N.
// mode 2 (SAGE, interleaved [Wl|Wr]): out = FT(h_un[M,F=N/2]) + atomic ssq.
__global__ __launch_bounds__(512, 2) void gemm_mfma(
    const bf16* __restrict__ A, int K,
    const bf16* __restrict__ Bt,
    const float* __restrict__ bias,
    bf16* __restrict__ out, int N, int mode,
    const float* __restrict__ gm, float* __restrict__ ssq) {
    __shared__ bf16 sA[2][16384];   // per buf: 32 slots (ksub*8 + rowblk) x 512
    __shared__ bf16 sB[2][16384];   // per buf: 32 slots (ksub*8 + colblk) x 512
    const int t = threadIdx.x;
    const int lane = t & 63;
    const int w = t >> 6;            // 0..7
    const int wr = w >> 2, wc = w & 3;   // per-wave out: 128 rows x 64 cols
    // XCD-aware swizzle (requires gridDim.y % 8 == 0)
    const int lin = blockIdx.x + gridDim.x * blockIdx.y;
    const int C = gridDim.x;
    const int cls = lin & 7;
    const int s0 = lin >> 3;
    const int rpc = gridDim.y >> 3;
    const int sy = s0 / C;
    const int row0 = (cls * rpc + sy) * 256;
    const int col0 = (s0 - sy * C) * 256;
    const int m32 = lane & 31;
    const int kh = lane >> 5;

    f32x16 acc[4][2] = {};

    const int TK = K >> 4;
    const int le = lane * 8;
    // wave w stages A row-block w and B col-block w of the 256-tile
    const bf16* gA = A  + (size_t)((row0 >> 5) + w) * TK * 512 + le;
    const bf16* gB = Bt + (size_t)((col0 >> 5) + w) * TK * 512 + le;

    const int NT = K >> 6;
    // prologue: stage K-tile 0 into buf 0 (8 glds16 in flight)
#pragma unroll
    for (int p = 0; p < 4; p++) {
        glds16(gA + p * 512, &sA[0][(p * 8 + w) * 512]);
        glds16(gB + p * 512, &sB[0][(p * 8 + w) * 512]);
    }

    for (int kt = 0; kt < NT; kt++) {
        const int cur = kt & 1;
        const size_t knext = (size_t)(kt + 1 < NT ? kt + 1 : kt) * 2048;
        const bf16* rA = &sA[cur][0];
        const bf16* rB = &sB[cur][0];
        bf16* dA = &sA[cur ^ 1][w * 512];
        bf16* dB = &sB[cur ^ 1][w * 512];
#pragma unroll
        for (int p = 0; p < 4; p++) {
            // oldest staging issue (this phase's slots) must land; 6 stay in flight
            asm volatile("s_waitcnt vmcnt(6)" ::: "memory");
            __builtin_amdgcn_s_barrier();
            asm volatile("" ::: "memory");
            bf16x8 af[4], bfr[2];
#pragma unroll
            for (int i = 0; i < 4; i++)
                af[i] = *(const bf16x8*)&rA[(p * 8 + wr * 4 + i) * 512 + le];
#pragma unroll
            for (int j = 0; j < 2; j++)
                bfr[j] = *(const bf16x8*)&rB[(p * 8 + wc * 2 + j) * 512 + le];
            // prefetch next K-tile, same phase-slots (2 glds16/phase, uniform)
            glds16(gA + knext + p * 512, dA + p * 8 * 512);
            glds16(gB + knext + p * 512, dB + p * 8 * 512);
            __builtin_amdgcn_s_setprio(1);
#pragma unroll
            for (int i = 0; i < 4; i++)
#pragma unroll
                for (int j = 0; j < 2; j++)
                    acc[i][j] = __builtin_amdgcn_mfma_f32_32x32x16_bf16(af[i], bfr[j], acc[i][j], 0, 0, 0);
            __builtin_amdgcn_s_setprio(0);
        }
    }
    // drain wrap-staged loads before LDS dealloc / epilogue
    asm volatile("s_waitcnt vmcnt(0)" ::: "memory");

    float g[16];
#pragma unroll
    for (int q = 0; q < 16; q++) g[q] = gm[q];

    if (mode == 1) {
        // GCN: node mix per reg-quad + bias + ReLU; write FT (next-K = N)
        const int Tn = N >> 4;
#pragma unroll
        for (int i = 0; i < 4; i++) {
            size_t RBo = (size_t)(row0 >> 5) + 4 * wr + i;
#pragma unroll
            for (int j = 0; j < 2; j++) {
                int c = col0 + (2 * wc + j) * 32 + m32;
                size_t tbase = (RBo * Tn + (c >> 4)) * 512;
                int coff = ((c >> 3) & 1) * 32;
                int cj = c & 7;
                float bsv = bias[c];
#pragma unroll
                for (int q = 0; q < 4; q++) {
#pragma unroll
                    for (int n = 0; n < 4; n++) {
                        float v = g[n * 4 + 0] * acc[i][j][q * 4 + 0] +
                                  g[n * 4 + 1] * acc[i][j][q * 4 + 1] +
                                  g[n * 4 + 2] * acc[i][j][q * 4 + 2] +
                                  g[n * 4 + 3] * acc[i][j][q * 4 + 3] + bsv;
                        out[tbase + (size_t)(coff + 4 * kh + 8 * q + n) * 8 + cj] =
                            (bf16)fmaxf(v, 0.f);
                    }
                }
            }
        }
    } else {
        // SAGE: even m32 = Wl col f (mix), odd = Wr col f (self); write FT(F)
        const int F = N >> 1;
        const int Tf = F >> 4;
        const bool ev = ((m32 & 1) == 0);
#pragma unroll
        for (int i = 0; i < 4; i++) {
            size_t RBo = (size_t)(row0 >> 5) + 4 * wr + i;
            int rbAbs = row0 + (4 * wr + i) * 32 + 4 * kh;
#pragma unroll
            for (int q = 0; q < 4; q++) {
                float ssql[4] = {0.f, 0.f, 0.f, 0.f};
#pragma unroll
                for (int j = 0; j < 2; j++) {
                    int c = col0 + (2 * wc + j) * 32 + m32;
                    int f = c >> 1;
                    size_t tbase = (RBo * Tf + (f >> 4)) * 512;
                    int foff = ((f >> 3) & 1) * 32;
                    int fj = f & 7;
                    float bsv = bias[f];
                    float mine[4];
                    if (ev) {
#pragma unroll
                        for (int n = 0; n < 4; n++)
                            mine[n] = g[n * 4 + 0] * acc[i][j][q * 4 + 0] +
                                      g[n * 4 + 1] * acc[i][j][q * 4 + 1] +
                                      g[n * 4 + 2] * acc[i][j][q * 4 + 2] +
                                      g[n * 4 + 3] * acc[i][j][q * 4 + 3];
                    } else {
#pragma unroll
                        for (int n = 0; n < 4; n++) mine[n] = acc[i][j][q * 4 + n];
                    }
#pragma unroll
                    for (int n = 0; n < 4; n++) {
                        float oth = __shfl_xor(mine[n], 1);
                        float tot = mine[n] + oth + bsv;
                        ssql[n] += tot * tot;
                        if (ev)
                            out[tbase + (size_t)(foff + 4 * kh + 8 * q + n) * 8 + fj] =
                                (bf16)tot;
                    }
                }
#pragma unroll
                for (int n = 0; n < 4; n++) {
                    float v = ssql[n];
                    v += __shfl_xor(v, 1); v += __shfl_xor(v, 2);
                    v += __shfl_xor(v, 4); v += __shfl_xor(v, 8);
                    v += __shfl_xor(v, 16);
                    ssql[n] = v;
                }
                if (m32 == 0) {
#pragma unroll
                    for (int n = 0; n < 4; n++)
                        atomicAdd(&ssq[rbAbs + 8 * q + n], ssql[n] * 0.5f);
                }
            }
        }
    }
}

// ---------- apply L2-norm + ReLU in place, FT layout -----------------------
// chunk idx: tile=idx>>6, row = (tile>>tsh)*32 + (idx&31); tsh = log2(F/16).
__global__ __launch_bounds__(256) void norm_apply(bf16x8* __restrict__ h,
                                                  const float* __restrict__ ssq,
                                                  int tsh) {
    int idx = blockIdx.x * 256 + threadIdx.x;
    int row = (((idx >> 6) >> tsh) << 5) | (idx & 31);
    float inv = 1.f / fmaxf(sqrtf(ssq[row]), 1e-12f);
    bf16x8 v = h[idx], o;
#pragma unroll
    for (int c = 0; c < 8; c++) o[c] = (bf16)fmaxf((float)v[c] * inv, 0.f);
    h[idx] = o;
}

// ---------- final FC (1024->10) + softmax, fused h4 norm+ReLU, FT input ----
// h4 FT[M,256] (T=16). Element e: rows 4e..4e+3 live in row-block e>>3 at
// m32 = 4*(e&7)+node. lane -> (ks=lane&15, node=lane>>4), jj loop = kh.
// FC feature index = node*256 + ks*16 + jj*8 + c  (node offset! R12 bug).
__global__ __launch_bounds__(256) void fc_softmax(const bf16x8* __restrict__ h,
                                                  const float* __restrict__ ssq4,
                                                  const float* __restrict__ Wfc,
                                                  const float* __restrict__ bfc,
                                                  float* __restrict__ outp) {
    __shared__ float WT[10][1024];
    int t = threadIdx.x;
    for (int i = t; i < 10240; i += 256) { int o = i % 10, k = i / 10; WT[o][k] = Wfc[i]; }
    __syncthreads();
    int wid = t >> 6, lane = t & 63;
    size_t e = (size_t)blockIdx.x * 4 + wid;
    size_t eb8 = e >> 3;
    int eo = (int)(e & 7);
    int ks = lane & 15, node = lane >> 4;
    float inv = 1.f / fmaxf(sqrtf(ssq4[e * 4 + node]), 1e-12f);
    float acc[10];
#pragma unroll
    for (int o = 0; o < 10; o++) acc[o] = 0.f;
#pragma unroll
    for (int jj = 0; jj < 2; jj++) {
        size_t ch = (eb8 * 16 + ks) * 64 + jj * 32 + eo * 4 + node;
        bf16x8 v = h[ch];
        float f[8];
#pragma unroll
        for (int c = 0; c < 8; c++) f[c] = fmaxf((float)v[c] * inv, 0.f);
        int k0 = node * 256 + ks * 16 + jj * 8;
#pragma unroll
        for (int o = 0; o < 10; o++) {
            const float* wr = &WT[o][k0];
            float s = 0.f;
#pragma unroll
            for (int c = 0; c < 8; c++) s += f[c] * wr[c];
            acc[o] += s;
        }
    }
#pragma unroll
    for (int o = 0; o < 10; o++) {
        float v = acc[o];
        v += __shfl_xor(v, 32); v += __shfl_xor(v, 16); v += __shfl_xor(v, 8);
        v += __shfl_xor(v, 4);  v += __shfl_xor(v, 2);  v += __shfl_xor(v, 1);
        acc[o] = v + bfc[o];
    }
    float mx = acc[0];
#pragma unroll
    for (int o = 1; o < 10; o++) mx = fmaxf(mx, acc[o]);
    float sum = 0.f, p[10];
#pragma unroll
    for (int o = 0; o < 10; o++) { p[o] = expf(acc[o] - mx); sum += p[o]; }
    float inv2 = 1.f / sum;
    if (lane < 10) outp[e * 10 + lane] = p[lane] * inv2;
}

// ---------------------------------------------------------------------------
extern "C" void kernel_launch(void* const* d_in, const int* in_sizes, int n_in,
                              void* d_out, int out_size, void* d_ws, size_t ws_size,
                              hipStream_t stream) {
    const float* x   = (const float*)d_in[0];
    const int*   ei  = (const int*)d_in[1];
    const float* W1  = (const float*)d_in[2];
    const float* b1  = (const float*)d_in[3];
    const float* Wl2 = (const float*)d_in[4];
    const float* bl2 = (const float*)d_in[5];
    const float* Wr2 = (const float*)d_in[6];
    const float* Wl3 = (const float*)d_in[7];
    const float* bl3 = (const float*)d_in[8];
    const float* Wr3 = (const float*)d_in[9];
    const float* Wl4 = (const float*)d_in[10];
    const float* bl4 = (const float*)d_in[11];
    const float* Wr4 = (const float*)d_in[12];
    const float* Wfc = (const float*)d_in[13];
    const float* bfc = (const float*)d_in[14];
    float* out = (float*)d_out;

    const int B = 32768;
    char* base = (char*)d_ws;
    float* gmat = (float*)base;
    bf16* Wt1 = (bf16*)(base + 4096);                  // FT [1024 x 64]
    bf16* Wt2 = Wt1 + 1024 * 64;                       // FT [1024 x 1024] interleaved
    bf16* Wt3 = Wt2 + 1024 * 1024;                     // FT [512 x 512]  interleaved
    bf16* Wt4 = Wt3 + 512 * 512;                       // FT [512 x 256]  interleaved
    char* sl  = (char*)(Wt4 + 512 * 256);
    size_t fixed = (size_t)(sl - base);

    // per-elem: R0 512B + R1 8192B + R2 4096B + ssq 48B = 12848 B
    int Bs = B;
    while (Bs > 512 && fixed + (size_t)Bs * 12848 > ws_size) Bs >>= 1;
    int nslice = B / Bs;
    int M = Bs * 4;

    bf16* R0 = (bf16*)sl;                       // xb FT [M,64]
    bf16* R1 = R0 + (size_t)Bs * 256;           // h1 FT [M,1024]; then h3_un FT [M,256]
    bf16* R2 = R1 + (size_t)Bs * 4096;          // h2_un FT [M,512]; then h4_un FT [M,256]
    float* ssqb = (float*)(R2 + (size_t)Bs * 2048);   // 3*M floats

    hipLaunchKernelGGL(k_setup, dim3(1), dim3(64), 0, stream, ei, gmat);
    hipLaunchKernelGGL(wtransF, dim3((1024 * 64 + 255) / 256), dim3(256), 0, stream,
                       W1, 64, 1024, Wt1);
    hipLaunchKernelGGL(wtransI, dim3((1024 * 1024 + 255) / 256), dim3(256), 0, stream,
                       Wl2, Wr2, 1024, 512, Wt2);
    hipLaunchKernelGGL(wtransI, dim3((512 * 512 + 255) / 256), dim3(256), 0, stream,
                       Wl3, Wr3, 512, 256, Wt3);
    hipLaunchKernelGGL(wtransI, dim3((512 * 256 + 255) / 256), dim3(256), 0, stream,
                       Wl4, Wr4, 256, 256, Wt4);

    for (int s = 0; s < nslice; s++) {
        const float* xs = x + (size_t)s * Bs * 256;
        hipLaunchKernelGGL(k_zero, dim3((3 * M / 4 + 255) / 256), dim3(256), 0, stream,
                           (float4*)ssqb, 3 * M / 4);
        hipLaunchKernelGGL(cast_x, dim3(Bs / 8), dim3(256), 0, stream,
                           (const float4*)xs, (bf16x8*)R0);
        // L1 GCN: h1 = relu(mix(x@W1) + b1)   [mode 1]  N=1024, K=64
        hipLaunchKernelGGL(gemm_mfma, dim3(4, M / 256), dim3(512), 0, stream,
                           R0, 64, Wt1, b1, R1, 1024, 1, gmat, (float*)nullptr);
        // L2 SAGE: h2_un (F=512) + ssq  [mode 2]  N=1024, K=1024
        hipLaunchKernelGGL(gemm_mfma, dim3(4, M / 256), dim3(512), 0, stream,
                           R1, 1024, Wt2, bl2, R2, 1024, 2, gmat + 16, ssqb);
        hipLaunchKernelGGL(norm_apply, dim3(M / 4), dim3(256), 0, stream,
                           (bf16x8*)R2, ssqb, 5);          // F=512 -> T=32 -> tsh=5
        // L3 SAGE: h3_un (F=256) into R1   N=512, K=512
        hipLaunchKernelGGL(gemm_mfma, dim3(2, M / 256), dim3(512), 0, stream,
                           R2, 512, Wt3, bl3, R1, 512, 2, gmat + 16, ssqb + M);
        hipLaunchKernelGGL(norm_apply, dim3(M / 8), dim3(256), 0, stream,
                           (bf16x8*)R1, ssqb + M, 4);      // F=256 -> T=16 -> tsh=4
        // L4 SAGE: h4_un (F=256) into R2   N=512, K=256
        hipLaunchKernelGGL(gemm_mfma, dim3(2, M / 256), dim3(512), 0, stream,
                           R1, 256, Wt4, bl4, R2, 512, 2, gmat + 16, ssqb + 2 * M);
        // FC + softmax with fused h4 norm+ReLU (FT input)
        hipLaunchKernelGGL(fc_softmax, dim3(Bs / 4), dim3(256), 0, stream,
                           (const bf16x8*)R2, ssqb + 2 * M, Wfc, bfc,
                           out + (size_t)s * Bs * 10);
    }
}

// Round 2
// 997.728 us; speedup vs baseline: 1.0235x; 1.0235x over previous
//
#include <hip/hip_runtime.h>
#include <stdint.h>
#include <math.h>

typedef __bf16 bf16;
typedef __attribute__((ext_vector_type(8))) __bf16 bf16x8;
typedef __attribute__((ext_vector_type(16))) float f32x16;

#define AS1 __attribute__((address_space(1)))
#define AS3 __attribute__((address_space(3)))

__device__ __forceinline__ void glds16(const void* g, void* l) {
    __builtin_amdgcn_global_load_lds((const AS1 uint32_t*)g, (AS3 uint32_t*)l, 16, 0, 0);
}

// Fragment-tile (FT) layout for X[M,K]: tile (rb=r>>5, ks=k>>4) is 512 elems:
// addr = (rb*(K/16)+ks)*512 + (((k>>3)&1)*32 + (r&31))*8 + (k&7).
// A wave's MFMA fragment = 1KB contiguous -> coalesced staging loads, 0 LDS
// bank conflicts (linear copy; read addr == write order).

// ---------- setup: A_gcn (gmat[0..15]) and M_sage (gmat[16..31]) -----------
__global__ void k_setup(const int* __restrict__ ei, float* __restrict__ gmat) {
    if (threadIdx.x != 0 || blockIdx.x != 0) return;
    bool is64 = true;
    for (int i = 0; i < 12; i++) if (ei[2 * i + 1] != 0) { is64 = false; break; }
    int src[12], dst[12];
    for (int e = 0; e < 12; e++) {
        if (is64) { src[e] = ei[2 * e]; dst[e] = ei[24 + 2 * e]; }
        else      { src[e] = ei[e];     dst[e] = ei[12 + e]; }
    }
    float deg[4] = {1.f, 1.f, 1.f, 1.f};
    for (int e = 0; e < 12; e++) deg[dst[e]] += 1.f;
    float dinv[4];
    for (int n = 0; n < 4; n++) dinv[n] = 1.f / sqrtf(deg[n]);
    float A[16];
    for (int i = 0; i < 16; i++) A[i] = 0.f;
    for (int e = 0; e < 12; e++) A[dst[e] * 4 + src[e]] += dinv[src[e]] * dinv[dst[e]];
    for (int n = 0; n < 4; n++) A[n * 4 + n] += dinv[n] * dinv[n];
    float cnt[4] = {0.f, 0.f, 0.f, 0.f};
    for (int e = 0; e < 12; e++) cnt[dst[e]] += 1.f;
    for (int n = 0; n < 4; n++) cnt[n] = fmaxf(cnt[n], 1.f);
    float Mm[16];
    for (int i = 0; i < 16; i++) Mm[i] = 0.f;
    for (int e = 0; e < 12; e++) Mm[dst[e] * 4 + src[e]] += 1.f;
    for (int n = 0; n < 4; n++)
        for (int m = 0; m < 4; m++) Mm[n * 4 + m] /= cnt[n];
    for (int i = 0; i < 16; i++) { gmat[i] = A[i]; gmat[16 + i] = Mm[i]; }
}

// ---------- W [K,N] -> Wt FT[N,K] bf16 -------------------------------------
__global__ __launch_bounds__(256) void wtransF(const float* __restrict__ W, int K,
                                               int N, bf16* __restrict__ Wt) {
    int a = blockIdx.x * 256 + threadIdx.x;
    if (a >= N * K) return;
    int j = a & 7, c64 = (a >> 3) & 63, tile = a >> 9;
    int m32 = c64 & 31, kh = c64 >> 5;
    int TK = K >> 4;
    int rblk = tile / TK, ks = tile - rblk * TK;
    int n = rblk * 32 + m32, k = ks * 16 + kh * 8 + j;
    Wt[a] = (bf16)W[(size_t)k * N + n];
}

// ---------- interleaved [Wl|Wr] -> Wt FT[2F,K]; row 2f->Wl, 2f+1->Wr -------
__global__ __launch_bounds__(256) void wtransI(const float* __restrict__ Wl,
                                               const float* __restrict__ Wr,
                                               int K, int F, bf16* __restrict__ Bt) {
    int a = blockIdx.x * 256 + threadIdx.x;
    if (a >= 2 * F * K) return;
    int j = a & 7, c64 = (a >> 3) & 63, tile = a >> 9;
    int m32 = c64 & 31, kh = c64 >> 5;
    int TK = K >> 4;
    int rblk = tile / TK, ks = tile - rblk * TK;
    int n = rblk * 32 + m32, k = ks * 16 + kh * 8 + j;
    int f = n >> 1;
    float v = (n & 1) ? Wr[(size_t)k * F + f] : Wl[(size_t)k * F + f];
    Bt[a] = (bf16)v;
}

// ---------- cast fp32 x [M,64] -> bf16 FT ----------------------------------
__global__ __launch_bounds__(256) void cast_x(const float4* __restrict__ x,
                                              bf16x8* __restrict__ out) {
    int i = blockIdx.x * 256 + threadIdx.x;   // chunk index over M*8
    int c64 = i & 63, m32 = c64 & 31, kh = c64 >> 5;
    int tile = i >> 6, RB = tile >> 2, ks = tile & 3;
    int row = RB * 32 + m32;
    int fb4 = ks * 4 + kh * 2;                // float4 index within 16/row
    float4 a = x[(size_t)row * 16 + fb4], b = x[(size_t)row * 16 + fb4 + 1];
    bf16x8 o;
    o[0] = (bf16)a.x; o[1] = (bf16)a.y; o[2] = (bf16)a.z; o[3] = (bf16)a.w;
    o[4] = (bf16)b.x; o[5] = (bf16)b.y; o[6] = (bf16)b.z; o[7] = (bf16)b.w;
    out[i] = o;
}

// ---------- zero ssq accumulators ------------------------------------------
__global__ __launch_bounds__(256) void k_zero(float4* __restrict__ p, int n4) {
    int i = blockIdx.x * 256 + threadIdx.x;
    if (i < n4) p[i] = make_float4(0.f, 0.f, 0.f, 0.f);
}

// ---------- MFMA GEMM, 256x256 tile, BK=64, 8 waves, fat-tile schedule -----
// One barrier + one vmcnt(0) per K-tile (slack = full tile body, so the wait
// is free in steady state). Double-buffered LDS, 1-tile prefetch distance.
// Inside the tile: 8x glds16 prefetch, then 4 ksubs x {6 ds_read_b128,
// 8 mfma_32x32x16} with NO internal barriers -> compiler's fine-grained
// lgkmcnt lets waves slip, overlapping LDS service with the matrix pipe.
// Race-freedom with ONE barrier: a wave's ds_reads of buf[b] complete before
// its MFMAs (lgkm waits), which complete before it reaches the next barrier,
// which precedes any glds16 write into buf[b].
// XCD swizzle is ROW-AFFINE: all col-tiles of an A row-panel run on the same
// XCD, temporally adjacent -> A panel fetched into that XCD's L2 once, hit by
// the other col-tiles (was: 4 XCDs each pulling the panel from L3/HBM).
// mode 1 (GCN): out = FT(mix4(A@Bt^T)+bias, ReLU) with next-K = N.
// mode 2 (SAGE, interleaved [Wl|Wr]): out = FT(h_un[M,F=N/2]) + atomic ssq.
__global__ __launch_bounds__(512, 2) void gemm_mfma(
    const bf16* __restrict__ A, int K,
    const bf16* __restrict__ Bt,
    const float* __restrict__ bias,
    bf16* __restrict__ out, int N, int mode,
    const float* __restrict__ gm, float* __restrict__ ssq) {
    __shared__ bf16 sA[2][16384];   // per buf: 32 slots (ksub*8 + rowblk) x 512
    __shared__ bf16 sB[2][16384];   // per buf: 32 slots (ksub*8 + colblk) x 512
    const int t = threadIdx.x;
    const int lane = t & 63;
    const int w = t >> 6;            // 0..7
    const int wr = w >> 2, wc = w & 3;   // per-wave out: 128 rows x 64 cols
    // Row-affine XCD swizzle (requires gridDim.y % 8 == 0)
    const int lin = blockIdx.x + gridDim.x * blockIdx.y;
    const int C = gridDim.x;
    const int xcd = lin & 7;
    const int seq = lin >> 3;
    const int rloc = seq / C;
    const int cloc = seq - rloc * C;
    const int row0 = (xcd + 8 * rloc) * 256;
    const int col0 = cloc * 256;
    const int m32 = lane & 31;
    const int kh = lane >> 5;

    f32x16 acc[4][2] = {};

    const int TK = K >> 4;
    const int le = lane * 8;
    // wave w stages A row-block w and B col-block w of the 256-tile
    const bf16* gA = A  + (size_t)((row0 >> 5) + w) * TK * 512 + le;
    const bf16* gB = Bt + (size_t)((col0 >> 5) + w) * TK * 512 + le;

    const int NT = K >> 6;
    // prologue: stage K-tile 0 into buf 0 (8 glds16 in flight)
#pragma unroll
    for (int p = 0; p < 4; p++) {
        glds16(gA + p * 512, &sA[0][(p * 8 + w) * 512]);
        glds16(gB + p * 512, &sB[0][(p * 8 + w) * 512]);
    }

    for (int kt = 0; kt < NT; kt++) {
        const int rb = kt & 1;
        const size_t knext = (size_t)(kt + 1 < NT ? kt + 1 : kt) * 2048;
        // this tile's 8 loads (issued a full tile-body ago) must have landed
        asm volatile("s_waitcnt vmcnt(0)" ::: "memory");
        __builtin_amdgcn_s_barrier();
        asm volatile("" ::: "memory");
        // prefetch next K-tile into the other buffer (safe: everyone is done
        // reading it as of the barrier above)
        bf16* dA = &sA[rb ^ 1][w * 512];
        bf16* dB = &sB[rb ^ 1][w * 512];
#pragma unroll
        for (int p = 0; p < 4; p++) {
            glds16(gA + knext + p * 512, dA + p * 8 * 512);
            glds16(gB + knext + p * 512, dB + p * 8 * 512);
        }
        const bf16* rA = &sA[rb][0];
        const bf16* rB = &sB[rb][0];
        __builtin_amdgcn_s_setprio(1);
#pragma unroll
        for (int p = 0; p < 4; p++) {
            bf16x8 af[4], bfr[2];
#pragma unroll
            for (int i = 0; i < 4; i++)
                af[i] = *(const bf16x8*)&rA[(p * 8 + wr * 4 + i) * 512 + le];
#pragma unroll
            for (int j = 0; j < 2; j++)
                bfr[j] = *(const bf16x8*)&rB[(p * 8 + wc * 2 + j) * 512 + le];
#pragma unroll
            for (int i = 0; i < 4; i++)
#pragma unroll
                for (int j = 0; j < 2; j++)
                    acc[i][j] = __builtin_amdgcn_mfma_f32_32x32x16_bf16(af[i], bfr[j], acc[i][j], 0, 0, 0);
        }
        __builtin_amdgcn_s_setprio(0);
    }
    // drain wrap-staged loads before LDS dealloc / epilogue
    asm volatile("s_waitcnt vmcnt(0)" ::: "memory");

    float g[16];
#pragma unroll
    for (int q = 0; q < 16; q++) g[q] = gm[q];

    if (mode == 1) {
        // GCN: node mix per reg-quad + bias + ReLU; write FT (next-K = N)
        const int Tn = N >> 4;
#pragma unroll
        for (int i = 0; i < 4; i++) {
            size_t RBo = (size_t)(row0 >> 5) + 4 * wr + i;
#pragma unroll
            for (int j = 0; j < 2; j++) {
                int c = col0 + (2 * wc + j) * 32 + m32;
                size_t tbase = (RBo * Tn + (c >> 4)) * 512;
                int coff = ((c >> 3) & 1) * 32;
                int cj = c & 7;
                float bsv = bias[c];
#pragma unroll
                for (int q = 0; q < 4; q++) {
#pragma unroll
                    for (int n = 0; n < 4; n++) {
                        float v = g[n * 4 + 0] * acc[i][j][q * 4 + 0] +
                                  g[n * 4 + 1] * acc[i][j][q * 4 + 1] +
                                  g[n * 4 + 2] * acc[i][j][q * 4 + 2] +
                                  g[n * 4 + 3] * acc[i][j][q * 4 + 3] + bsv;
                        out[tbase + (size_t)(coff + 4 * kh + 8 * q + n) * 8 + cj] =
                            (bf16)fmaxf(v, 0.f);
                    }
                }
            }
        }
    } else {
        // SAGE: even m32 = Wl col f (mix), odd = Wr col f (self); write FT(F)
        const int F = N >> 1;
        const int Tf = F >> 4;
        const bool ev = ((m32 & 1) == 0);
#pragma unroll
        for (int i = 0; i < 4; i++) {
            size_t RBo = (size_t)(row0 >> 5) + 4 * wr + i;
            int rbAbs = row0 + (4 * wr + i) * 32 + 4 * kh;
#pragma unroll
            for (int q = 0; q < 4; q++) {
                float ssql[4] = {0.f, 0.f, 0.f, 0.f};
#pragma unroll
                for (int j = 0; j < 2; j++) {
                    int c = col0 + (2 * wc + j) * 32 + m32;
                    int f = c >> 1;
                    size_t tbase = (RBo * Tf + (f >> 4)) * 512;
                    int foff = ((f >> 3) & 1) * 32;
                    int fj = f & 7;
                    float bsv = bias[f];
                    float mine[4];
                    if (ev) {
#pragma unroll
                        for (int n = 0; n < 4; n++)
                            mine[n] = g[n * 4 + 0] * acc[i][j][q * 4 + 0] +
                                      g[n * 4 + 1] * acc[i][j][q * 4 + 1] +
                                      g[n * 4 + 2] * acc[i][j][q * 4 + 2] +
                                      g[n * 4 + 3] * acc[i][j][q * 4 + 3];
                    } else {
#pragma unroll
                        for (int n = 0; n < 4; n++) mine[n] = acc[i][j][q * 4 + n];
                    }
#pragma unroll
                    for (int n = 0; n < 4; n++) {
                        float oth = __shfl_xor(mine[n], 1);
                        float tot = mine[n] + oth + bsv;
                        ssql[n] += tot * tot;
                        if (ev)
                            out[tbase + (size_t)(foff + 4 * kh + 8 * q + n) * 8 + fj] =
                                (bf16)tot;
                    }
                }
#pragma unroll
                for (int n = 0; n < 4; n++) {
                    float v = ssql[n];
                    v += __shfl_xor(v, 1); v += __shfl_xor(v, 2);
                    v += __shfl_xor(v, 4); v += __shfl_xor(v, 8);
                    v += __shfl_xor(v, 16);
                    ssql[n] = v;
                }
                if (m32 == 0) {
#pragma unroll
                    for (int n = 0; n < 4; n++)
                        atomicAdd(&ssq[rbAbs + 8 * q + n], ssql[n] * 0.5f);
                }
            }
        }
    }
}

// ---------- apply L2-norm + ReLU in place, FT layout -----------------------
// chunk idx: tile=idx>>6, row = (tile>>tsh)*32 + (idx&31); tsh = log2(F/16).
__global__ __launch_bounds__(256) void norm_apply(bf16x8* __restrict__ h,
                                                  const float* __restrict__ ssq,
                                                  int tsh) {
    int idx = blockIdx.x * 256 + threadIdx.x;
    int row = (((idx >> 6) >> tsh) << 5) | (idx & 31);
    float inv = 1.f / fmaxf(sqrtf(ssq[row]), 1e-12f);
    bf16x8 v = h[idx], o;
#pragma unroll
    for (int c = 0; c < 8; c++) o[c] = (bf16)fmaxf((float)v[c] * inv, 0.f);
    h[idx] = o;
}

// ---------- final FC (1024->10) + softmax, fused h4 norm+ReLU, FT input ----
// h4 FT[M,256] (T=16). Element e: rows 4e..4e+3 live in row-block e>>3 at
// m32 = 4*(e&7)+node. lane -> (ks=lane&15, node=lane>>4), jj loop = kh.
// FC feature index = node*256 + ks*16 + jj*8 + c  (node offset! R12 bug).
__global__ __launch_bounds__(256) void fc_softmax(const bf16x8* __restrict__ h,
                                                  const float* __restrict__ ssq4,
                                                  const float* __restrict__ Wfc,
                                                  const float* __restrict__ bfc,
                                                  float* __restrict__ outp) {
    __shared__ float WT[10][1024];
    int t = threadIdx.x;
    for (int i = t; i < 10240; i += 256) { int o = i % 10, k = i / 10; WT[o][k] = Wfc[i]; }
    __syncthreads();
    int wid = t >> 6, lane = t & 63;
    size_t e = (size_t)blockIdx.x * 4 + wid;
    size_t eb8 = e >> 3;
    int eo = (int)(e & 7);
    int ks = lane & 15, node = lane >> 4;
    float inv = 1.f / fmaxf(sqrtf(ssq4[e * 4 + node]), 1e-12f);
    float acc[10];
#pragma unroll
    for (int o = 0; o < 10; o++) acc[o] = 0.f;
#pragma unroll
    for (int jj = 0; jj < 2; jj++) {
        size_t ch = (eb8 * 16 + ks) * 64 + jj * 32 + eo * 4 + node;
        bf16x8 v = h[ch];
        float f[8];
#pragma unroll
        for (int c = 0; c < 8; c++) f[c] = fmaxf((float)v[c] * inv, 0.f);
        int k0 = node * 256 + ks * 16 + jj * 8;
#pragma unroll
        for (int o = 0; o < 10; o++) {
            const float* wr = &WT[o][k0];
            float s = 0.f;
#pragma unroll
            for (int c = 0; c < 8; c++) s += f[c] * wr[c];
            acc[o] += s;
        }
    }
#pragma unroll
    for (int o = 0; o < 10; o++) {
        float v = acc[o];
        v += __shfl_xor(v, 32); v += __shfl_xor(v, 16); v += __shfl_xor(v, 8);
        v += __shfl_xor(v, 4);  v += __shfl_xor(v, 2);  v += __shfl_xor(v, 1);
        acc[o] = v + bfc[o];
    }
    float mx = acc[0];
#pragma unroll
    for (int o = 1; o < 10; o++) mx = fmaxf(mx, acc[o]);
    float sum = 0.f, p[10];
#pragma unroll
    for (int o = 0; o < 10; o++) { p[o] = expf(acc[o] - mx); sum += p[o]; }
    float inv2 = 1.f / sum;
    if (lane < 10) outp[e * 10 + lane] = p[lane] * inv2;
}

// ---------------------------------------------------------------------------
extern "C" void kernel_launch(void* const* d_in, const int* in_sizes, int n_in,
                              void* d_out, int out_size, void* d_ws, size_t ws_size,
                              hipStream_t stream) {
    const float* x   = (const float*)d_in[0];
    const int*   ei  = (const int*)d_in[1];
    const float* W1  = (const float*)d_in[2];
    const float* b1  = (const float*)d_in[3];
    const float* Wl2 = (const float*)d_in[4];
    const float* bl2 = (const float*)d_in[5];
    const float* Wr2 = (const float*)d_in[6];
    const float* Wl3 = (const float*)d_in[7];
    const float* bl3 = (const float*)d_in[8];
    const float* Wr3 = (const float*)d_in[9];
    const float* Wl4 = (const float*)d_in[10];
    const float* bl4 = (const float*)d_in[11];
    const float* Wr4 = (const float*)d_in[12];
    const float* Wfc = (const float*)d_in[13];
    const float* bfc = (const float*)d_in[14];
    float* out = (float*)d_out;

    const int B = 32768;
    char* base = (char*)d_ws;
    float* gmat = (float*)base;
    bf16* Wt1 = (bf16*)(base + 4096);                  // FT [1024 x 64]
    bf16* Wt2 = Wt1 + 1024 * 64;                       // FT [1024 x 1024] interleaved
    bf16* Wt3 = Wt2 + 1024 * 1024;                     // FT [512 x 512]  interleaved
    bf16* Wt4 = Wt3 + 512 * 512;                       // FT [512 x 256]  interleaved
    char* sl  = (char*)(Wt4 + 512 * 256);
    size_t fixed = (size_t)(sl - base);

    // per-elem: R0 512B + R1 8192B + R2 4096B + ssq 48B = 12848 B
    int Bs = B;
    while (Bs > 512 && fixed + (size_t)Bs * 12848 > ws_size) Bs >>= 1;
    int nslice = B / Bs;
    int M = Bs * 4;

    bf16* R0 = (bf16*)sl;                       // xb FT [M,64]
    bf16* R1 = R0 + (size_t)Bs * 256;           // h1 FT [M,1024]; then h3_un FT [M,256]
    bf16* R2 = R1 + (size_t)Bs * 4096;          // h2_un FT [M,512]; then h4_un FT [M,256]
    float* ssqb = (float*)(R2 + (size_t)Bs * 2048);   // 3*M floats

    hipLaunchKernelGGL(k_setup, dim3(1), dim3(64), 0, stream, ei, gmat);
    hipLaunchKernelGGL(wtransF, dim3((1024 * 64 + 255) / 256), dim3(256), 0, stream,
                       W1, 64, 1024, Wt1);
    hipLaunchKernelGGL(wtransI, dim3((1024 * 1024 + 255) / 256), dim3(256), 0, stream,
                       Wl2, Wr2, 1024, 512, Wt2);
    hipLaunchKernelGGL(wtransI, dim3((512 * 512 + 255) / 256), dim3(256), 0, stream,
                       Wl3, Wr3, 512, 256, Wt3);
    hipLaunchKernelGGL(wtransI, dim3((512 * 256 + 255) / 256), dim3(256), 0, stream,
                       Wl4, Wr4, 256, 256, Wt4);

    for (int s = 0; s < nslice; s++) {
        const float* xs = x + (size_t)s * Bs * 256;
        hipLaunchKernelGGL(k_zero, dim3((3 * M / 4 + 255) / 256), dim3(256), 0, stream,
                           (float4*)ssqb, 3 * M / 4);
        hipLaunchKernelGGL(cast_x, dim3(Bs / 8), dim3(256), 0, stream,
                           (const float4*)xs, (bf16x8*)R0);
        // L1 GCN: h1 = relu(mix(x@W1) + b1)   [mode 1]  N=1024, K=64
        hipLaunchKernelGGL(gemm_mfma, dim3(4, M / 256), dim3(512), 0, stream,
                           R0, 64, Wt1, b1, R1, 1024, 1, gmat, (float*)nullptr);
        // L2 SAGE: h2_un (F=512) + ssq  [mode 2]  N=1024, K=1024
        hipLaunchKernelGGL(gemm_mfma, dim3(4, M / 256), dim3(512), 0, stream,
                           R1, 1024, Wt2, bl2, R2, 1024, 2, gmat + 16, ssqb);
        hipLaunchKernelGGL(norm_apply, dim3(M / 4), dim3(256), 0, stream,
                           (bf16x8*)R2, ssqb, 5);          // F=512 -> T=32 -> tsh=5
        // L3 SAGE: h3_un (F=256) into R1   N=512, K=512
        hipLaunchKernelGGL(gemm_mfma, dim3(2, M / 256), dim3(512), 0, stream,
                           R2, 512, Wt3, bl3, R1, 512, 2, gmat + 16, ssqb + M);
        hipLaunchKernelGGL(norm_apply, dim3(M / 8), dim3(256), 0, stream,
                           (bf16x8*)R1, ssqb + M, 4);      // F=256 -> T=16 -> tsh=4
        // L4 SAGE: h4_un (F=256) into R2   N=512, K=256
        hipLaunchKernelGGL(gemm_mfma, dim3(2, M / 256), dim3(512), 0, stream,
                           R1, 256, Wt4, bl4, R2, 512, 2, gmat + 16, ssqb + 2 * M);
        // FC + softmax with fused h4 norm+ReLU (FT input)
        hipLaunchKernelGGL(fc_softmax, dim3(Bs / 4), dim3(256), 0, stream,
                           (const bf16x8*)R2, ssqb + 2 * M, Wfc, bfc,
                           out + (size_t)s * Bs * 10);
    }
}

// Round 3
// 964.256 us; speedup vs baseline: 1.0590x; 1.0347x over previous
//
#include <hip/hip_runtime.h>
#include <stdint.h>
#include <math.h>

typedef __bf16 bf16;
typedef __attribute__((ext_vector_type(8))) __bf16 bf16x8;
typedef __attribute__((ext_vector_type(16))) float f32x16;

#define AS1 __attribute__((address_space(1)))
#define AS3 __attribute__((address_space(3)))

__device__ __forceinline__ void glds16(const void* g, void* l) {
    __builtin_amdgcn_global_load_lds((const AS1 uint32_t*)g, (AS3 uint32_t*)l, 16, 0, 0);
}

// Fragment-tile (FT) layout for X[M,K]: tile (rb=r>>5, ks=k>>4) is 512 elems:
// addr = (rb*(K/16)+ks)*512 + (((k>>3)&1)*32 + (r&31))*8 + (k&7).
// A wave's MFMA fragment = 1KB contiguous -> coalesced staging loads, 0 LDS
// bank conflicts (linear copy; read addr == write order).

// ---------- setup: A_gcn (gmat[0..15]) and M_sage (gmat[16..31]) -----------
__global__ void k_setup(const int* __restrict__ ei, float* __restrict__ gmat) {
    if (threadIdx.x != 0 || blockIdx.x != 0) return;
    bool is64 = true;
    for (int i = 0; i < 12; i++) if (ei[2 * i + 1] != 0) { is64 = false; break; }
    int src[12], dst[12];
    for (int e = 0; e < 12; e++) {
        if (is64) { src[e] = ei[2 * e]; dst[e] = ei[24 + 2 * e]; }
        else      { src[e] = ei[e];     dst[e] = ei[12 + e]; }
    }
    float deg[4] = {1.f, 1.f, 1.f, 1.f};
    for (int e = 0; e < 12; e++) deg[dst[e]] += 1.f;
    float dinv[4];
    for (int n = 0; n < 4; n++) dinv[n] = 1.f / sqrtf(deg[n]);
    float A[16];
    for (int i = 0; i < 16; i++) A[i] = 0.f;
    for (int e = 0; e < 12; e++) A[dst[e] * 4 + src[e]] += dinv[src[e]] * dinv[dst[e]];
    for (int n = 0; n < 4; n++) A[n * 4 + n] += dinv[n] * dinv[n];
    float cnt[4] = {0.f, 0.f, 0.f, 0.f};
    for (int e = 0; e < 12; e++) cnt[dst[e]] += 1.f;
    for (int n = 0; n < 4; n++) cnt[n] = fmaxf(cnt[n], 1.f);
    float Mm[16];
    for (int i = 0; i < 16; i++) Mm[i] = 0.f;
    for (int e = 0; e < 12; e++) Mm[dst[e] * 4 + src[e]] += 1.f;
    for (int n = 0; n < 4; n++)
        for (int m = 0; m < 4; m++) Mm[n * 4 + m] /= cnt[n];
    for (int i = 0; i < 16; i++) { gmat[i] = A[i]; gmat[16 + i] = Mm[i]; }
}

// ---------- W [K,N] -> Wt FT[N,K] bf16 -------------------------------------
__global__ __launch_bounds__(256) void wtransF(const float* __restrict__ W, int K,
                                               int N, bf16* __restrict__ Wt) {
    int a = blockIdx.x * 256 + threadIdx.x;
    if (a >= N * K) return;
    int j = a & 7, c64 = (a >> 3) & 63, tile = a >> 9;
    int m32 = c64 & 31, kh = c64 >> 5;
    int TK = K >> 4;
    int rblk = tile / TK, ks = tile - rblk * TK;
    int n = rblk * 32 + m32, k = ks * 16 + kh * 8 + j;
    Wt[a] = (bf16)W[(size_t)k * N + n];
}

// ---------- interleaved [Wl|Wr] -> Wt FT[2F,K]; row 2f->Wl, 2f+1->Wr -------
__global__ __launch_bounds__(256) void wtransI(const float* __restrict__ Wl,
                                               const float* __restrict__ Wr,
                                               int K, int F, bf16* __restrict__ Bt) {
    int a = blockIdx.x * 256 + threadIdx.x;
    if (a >= 2 * F * K) return;
    int j = a & 7, c64 = (a >> 3) & 63, tile = a >> 9;
    int m32 = c64 & 31, kh = c64 >> 5;
    int TK = K >> 4;
    int rblk = tile / TK, ks = tile - rblk * TK;
    int n = rblk * 32 + m32, k = ks * 16 + kh * 8 + j;
    int f = n >> 1;
    float v = (n & 1) ? Wr[(size_t)k * F + f] : Wl[(size_t)k * F + f];
    Bt[a] = (bf16)v;
}

// ---------- cast fp32 x [M,64] -> bf16 FT ----------------------------------
__global__ __launch_bounds__(256) void cast_x(const float4* __restrict__ x,
                                              bf16x8* __restrict__ out) {
    int i = blockIdx.x * 256 + threadIdx.x;   // chunk index over M*8
    int c64 = i & 63, m32 = c64 & 31, kh = c64 >> 5;
    int tile = i >> 6, RB = tile >> 2, ks = tile & 3;
    int row = RB * 32 + m32;
    int fb4 = ks * 4 + kh * 2;                // float4 index within 16/row
    float4 a = x[(size_t)row * 16 + fb4], b = x[(size_t)row * 16 + fb4 + 1];
    bf16x8 o;
    o[0] = (bf16)a.x; o[1] = (bf16)a.y; o[2] = (bf16)a.z; o[3] = (bf16)a.w;
    o[4] = (bf16)b.x; o[5] = (bf16)b.y; o[6] = (bf16)b.z; o[7] = (bf16)b.w;
    out[i] = o;
}

// ---------- zero ssq accumulators ------------------------------------------
__global__ __launch_bounds__(256) void k_zero(float4* __restrict__ p, int n4) {
    int i = blockIdx.x * 256 + threadIdx.x;
    if (i < n4) p[i] = make_float4(0.f, 0.f, 0.f, 0.f);
}

// ---------- MFMA GEMM, 256x256 tile, BK=64, 8 waves, m201 phase template ---
// 4 phases per K-tile, each phase (verified m201 ordering, adapted 32x32x16):
//   { 6x ds_read_b128 (af[4], bfr[2]) -> 2x glds16 next-tile prefetch ->
//     barrier -> lgkmcnt(0) + sched_barrier(0) -> setprio(1) -> 8 indep MFMA
//     -> setprio(0) -> barrier }
// Reads issued BEFORE the barrier, consumed after -> LDS service overlaps the
// barrier-arrival window + staggered lgkm drains (m196: this interleave is
// the lever; coarse split without it is -7..-27%). Prefetch spread A:ph0-1,
// B:ph2-3; single vmcnt(0) at ph3 before tile-end barrier (next tile's
// readers are gated by that barrier; all waves drained their own loads).
// Race-freedom: glds16 into buf^1 issues only after the tile-end barrier of
// the tile that last read buf^1 (all reads reg-consumed via lgkmcnt(0)).
// mode 1 (GCN): out = FT(mix4(A@Bt^T)+bias, ReLU) with next-K = N.
// mode 2 (SAGE, interleaved [Wl|Wr]): out = FT(h_un[M,F=N/2]) + atomic ssq.
__global__ __launch_bounds__(512, 2) void gemm_mfma(
    const bf16* __restrict__ A, int K,
    const bf16* __restrict__ Bt,
    const float* __restrict__ bias,
    bf16* __restrict__ out, int N, int mode,
    const float* __restrict__ gm, float* __restrict__ ssq) {
    __shared__ bf16 sA[2][16384];   // per buf: 32 slots (ksub*8 + rowblk) x 512
    __shared__ bf16 sB[2][16384];   // per buf: 32 slots (ksub*8 + colblk) x 512
    const int t = threadIdx.x;
    const int lane = t & 63;
    const int w = t >> 6;            // 0..7
    const int wr = w >> 2, wc = w & 3;   // per-wave out: 128 rows x 64 cols
    // Row-affine XCD swizzle (requires gridDim.y % 8 == 0)
    const int lin = blockIdx.x + gridDim.x * blockIdx.y;
    const int C = gridDim.x;
    const int xcd = lin & 7;
    const int seq = lin >> 3;
    const int rloc = seq / C;
    const int cloc = seq - rloc * C;
    const int row0 = (xcd + 8 * rloc) * 256;
    const int col0 = cloc * 256;
    const int m32 = lane & 31;
    const int kh = lane >> 5;

    f32x16 acc[4][2] = {};

    const int TK = K >> 4;
    const int le = lane * 8;
    // wave w stages A row-block w and B col-block w of the 256-tile
    const bf16* gA = A  + (size_t)((row0 >> 5) + w) * TK * 512 + le;
    const bf16* gB = Bt + (size_t)((col0 >> 5) + w) * TK * 512 + le;

    const int NT = K >> 6;
    // prologue: stage K-tile 0 into buf 0 and drain it
#pragma unroll
    for (int p = 0; p < 4; p++) {
        glds16(gA + p * 512, &sA[0][(p * 8 + w) * 512]);
        glds16(gB + p * 512, &sB[0][(p * 8 + w) * 512]);
    }
    asm volatile("s_waitcnt vmcnt(0)" ::: "memory");
    __builtin_amdgcn_s_barrier();

    for (int kt = 0; kt < NT; kt++) {
        const int cur = kt & 1;
        const size_t knext = (size_t)(kt + 1 < NT ? kt + 1 : kt) * 2048;
        const bf16* rA = &sA[cur][0];
        const bf16* rB = &sB[cur][0];
        bf16* dA = &sA[cur ^ 1][w * 512];
        bf16* dB = &sB[cur ^ 1][w * 512];
#pragma unroll
        for (int p = 0; p < 4; p++) {
            // phase-top LDS->reg fragment reads (consumed after the barrier)
            bf16x8 af[4], bfr[2];
#pragma unroll
            for (int i = 0; i < 4; i++)
                af[i] = *(const bf16x8*)&rA[(p * 8 + wr * 4 + i) * 512 + le];
#pragma unroll
            for (int j = 0; j < 2; j++)
                bfr[j] = *(const bf16x8*)&rB[(p * 8 + wc * 2 + j) * 512 + le];
            // next-tile prefetch, 2 glds16/phase (A in ph0-1, B in ph2-3)
            if (p == 0) {
                glds16(gA + knext,           dA);
                glds16(gA + knext + 512,     dA + 8 * 512);
            } else if (p == 1) {
                glds16(gA + knext + 2 * 512, dA + 16 * 512);
                glds16(gA + knext + 3 * 512, dA + 24 * 512);
            } else if (p == 2) {
                glds16(gB + knext,           dB);
                glds16(gB + knext + 512,     dB + 8 * 512);
            } else {
                glds16(gB + knext + 2 * 512, dB + 16 * 512);
                glds16(gB + knext + 3 * 512, dB + 24 * 512);
            }
            asm volatile("" ::: "memory");   // pin reads/issues before barrier
            __builtin_amdgcn_s_barrier();
            asm volatile("s_waitcnt lgkmcnt(0)" ::: "memory");
            __builtin_amdgcn_sched_barrier(0);   // rule #18: no MFMA hoisting
            __builtin_amdgcn_s_setprio(1);
#pragma unroll
            for (int i = 0; i < 4; i++)
#pragma unroll
                for (int j = 0; j < 2; j++)
                    acc[i][j] = __builtin_amdgcn_mfma_f32_32x32x16_bf16(af[i], bfr[j], acc[i][j], 0, 0, 0);
            __builtin_amdgcn_s_setprio(0);
            if (p == 3)   // drain next tile's 8 prefetches before its readers
                asm volatile("s_waitcnt vmcnt(0)" ::: "memory");
            __builtin_amdgcn_s_barrier();
        }
    }

    float g[16];
#pragma unroll
    for (int q = 0; q < 16; q++) g[q] = gm[q];

    if (mode == 1) {
        // GCN: node mix per reg-quad + bias + ReLU; write FT (next-K = N)
        const int Tn = N >> 4;
#pragma unroll
        for (int i = 0; i < 4; i++) {
            size_t RBo = (size_t)(row0 >> 5) + 4 * wr + i;
#pragma unroll
            for (int j = 0; j < 2; j++) {
                int c = col0 + (2 * wc + j) * 32 + m32;
                size_t tbase = (RBo * Tn + (c >> 4)) * 512;
                int coff = ((c >> 3) & 1) * 32;
                int cj = c & 7;
                float bsv = bias[c];
#pragma unroll
                for (int q = 0; q < 4; q++) {
#pragma unroll
                    for (int n = 0; n < 4; n++) {
                        float v = g[n * 4 + 0] * acc[i][j][q * 4 + 0] +
                                  g[n * 4 + 1] * acc[i][j][q * 4 + 1] +
                                  g[n * 4 + 2] * acc[i][j][q * 4 + 2] +
                                  g[n * 4 + 3] * acc[i][j][q * 4 + 3] + bsv;
                        out[tbase + (size_t)(coff + 4 * kh + 8 * q + n) * 8 + cj] =
                            (bf16)fmaxf(v, 0.f);
                    }
                }
            }
        }
    } else {
        // SAGE: even m32 = Wl col f (mix), odd = Wr col f (self); write FT(F)
        const int F = N >> 1;
        const int Tf = F >> 4;
        const bool ev = ((m32 & 1) == 0);
#pragma unroll
        for (int i = 0; i < 4; i++) {
            size_t RBo = (size_t)(row0 >> 5) + 4 * wr + i;
            int rbAbs = row0 + (4 * wr + i) * 32 + 4 * kh;
#pragma unroll
            for (int q = 0; q < 4; q++) {
                float ssql[4] = {0.f, 0.f, 0.f, 0.f};
#pragma unroll
                for (int j = 0; j < 2; j++) {
                    int c = col0 + (2 * wc + j) * 32 + m32;
                    int f = c >> 1;
                    size_t tbase = (RBo * Tf + (f >> 4)) * 512;
                    int foff = ((f >> 3) & 1) * 32;
                    int fj = f & 7;
                    float bsv = bias[f];
                    float mine[4];
                    if (ev) {
#pragma unroll
                        for (int n = 0; n < 4; n++)
                            mine[n] = g[n * 4 + 0] * acc[i][j][q * 4 + 0] +
                                      g[n * 4 + 1] * acc[i][j][q * 4 + 1] +
                                      g[n * 4 + 2] * acc[i][j][q * 4 + 2] +
                                      g[n * 4 + 3] * acc[i][j][q * 4 + 3];
                    } else {
#pragma unroll
                        for (int n = 0; n < 4; n++) mine[n] = acc[i][j][q * 4 + n];
                    }
#pragma unroll
                    for (int n = 0; n < 4; n++) {
                        float oth = __shfl_xor(mine[n], 1);
                        float tot = mine[n] + oth + bsv;
                        ssql[n] += tot * tot;
                        if (ev)
                            out[tbase + (size_t)(foff + 4 * kh + 8 * q + n) * 8 + fj] =
                                (bf16)tot;
                    }
                }
#pragma unroll
                for (int n = 0; n < 4; n++) {
                    float v = ssql[n];
                    v += __shfl_xor(v, 1); v += __shfl_xor(v, 2);
                    v += __shfl_xor(v, 4); v += __shfl_xor(v, 8);
                    v += __shfl_xor(v, 16);
                    ssql[n] = v;
                }
                if (m32 == 0) {
#pragma unroll
                    for (int n = 0; n < 4; n++)
                        atomicAdd(&ssq[rbAbs + 8 * q + n], ssql[n] * 0.5f);
                }
            }
        }
    }
}

// ---------- apply L2-norm + ReLU in place, FT layout -----------------------
// chunk idx: tile=idx>>6, row = (tile>>tsh)*32 + (idx&31); tsh = log2(F/16).
__global__ __launch_bounds__(256) void norm_apply(bf16x8* __restrict__ h,
                                                  const float* __restrict__ ssq,
                                                  int tsh) {
    int idx = blockIdx.x * 256 + threadIdx.x;
    int row = (((idx >> 6) >> tsh) << 5) | (idx & 31);
    float inv = 1.f / fmaxf(sqrtf(ssq[row]), 1e-12f);
    bf16x8 v = h[idx], o;
#pragma unroll
    for (int c = 0; c < 8; c++) o[c] = (bf16)fmaxf((float)v[c] * inv, 0.f);
    h[idx] = o;
}

// ---------- final FC (1024->10) + softmax, fused h4 norm+ReLU, FT input ----
// h4 FT[M,256] (T=16). Element e: rows 4e..4e+3 live in row-block e>>3 at
// m32 = 4*(e&7)+node. lane -> (ks=lane&15, node=lane>>4), jj loop = kh.
// FC feature index = node*256 + ks*16 + jj*8 + c  (node offset! R12 bug).
__global__ __launch_bounds__(256) void fc_softmax(const bf16x8* __restrict__ h,
                                                  const float* __restrict__ ssq4,
                                                  const float* __restrict__ Wfc,
                                                  const float* __restrict__ bfc,
                                                  float* __restrict__ outp) {
    __shared__ float WT[10][1024];
    int t = threadIdx.x;
    for (int i = t; i < 10240; i += 256) { int o = i % 10, k = i / 10; WT[o][k] = Wfc[i]; }
    __syncthreads();
    int wid = t >> 6, lane = t & 63;
    size_t e = (size_t)blockIdx.x * 4 + wid;
    size_t eb8 = e >> 3;
    int eo = (int)(e & 7);
    int ks = lane & 15, node = lane >> 4;
    float inv = 1.f / fmaxf(sqrtf(ssq4[e * 4 + node]), 1e-12f);
    float acc[10];
#pragma unroll
    for (int o = 0; o < 10; o++) acc[o] = 0.f;
#pragma unroll
    for (int jj = 0; jj < 2; jj++) {
        size_t ch = (eb8 * 16 + ks) * 64 + jj * 32 + eo * 4 + node;
        bf16x8 v = h[ch];
        float f[8];
#pragma unroll
        for (int c = 0; c < 8; c++) f[c] = fmaxf((float)v[c] * inv, 0.f);
        int k0 = node * 256 + ks * 16 + jj * 8;
#pragma unroll
        for (int o = 0; o < 10; o++) {
            const float* wr = &WT[o][k0];
            float s = 0.f;
#pragma unroll
            for (int c = 0; c < 8; c++) s += f[c] * wr[c];
            acc[o] += s;
        }
    }
#pragma unroll
    for (int o = 0; o < 10; o++) {
        float v = acc[o];
        v += __shfl_xor(v, 32); v += __shfl_xor(v, 16); v += __shfl_xor(v, 8);
        v += __shfl_xor(v, 4);  v += __shfl_xor(v, 2);  v += __shfl_xor(v, 1);
        acc[o] = v + bfc[o];
    }
    float mx = acc[0];
#pragma unroll
    for (int o = 1; o < 10; o++) mx = fmaxf(mx, acc[o]);
    float sum = 0.f, p[10];
#pragma unroll
    for (int o = 0; o < 10; o++) { p[o] = expf(acc[o] - mx); sum += p[o]; }
    float inv2 = 1.f / sum;
    if (lane < 10) outp[e * 10 + lane] = p[lane] * inv2;
}

// ---------------------------------------------------------------------------
extern "C" void kernel_launch(void* const* d_in, const int* in_sizes, int n_in,
                              void* d_out, int out_size, void* d_ws, size_t ws_size,
                              hipStream_t stream) {
    const float* x   = (const float*)d_in[0];
    const int*   ei  = (const int*)d_in[1];
    const float* W1  = (const float*)d_in[2];
    const float* b1  = (const float*)d_in[3];
    const float* Wl2 = (const float*)d_in[4];
    const float* bl2 = (const float*)d_in[5];
    const float* Wr2 = (const float*)d_in[6];
    const float* Wl3 = (const float*)d_in[7];
    const float* bl3 = (const float*)d_in[8];
    const float* Wr3 = (const float*)d_in[9];
    const float* Wl4 = (const float*)d_in[10];
    const float* bl4 = (const float*)d_in[11];
    const float* Wr4 = (const float*)d_in[12];
    const float* Wfc = (const float*)d_in[13];
    const float* bfc = (const float*)d_in[14];
    float* out = (float*)d_out;

    const int B = 32768;
    char* base = (char*)d_ws;
    float* gmat = (float*)base;
    bf16* Wt1 = (bf16*)(base + 4096);                  // FT [1024 x 64]
    bf16* Wt2 = Wt1 + 1024 * 64;                       // FT [1024 x 1024] interleaved
    bf16* Wt3 = Wt2 + 1024 * 1024;                     // FT [512 x 512]  interleaved
    bf16* Wt4 = Wt3 + 512 * 512;                       // FT [512 x 256]  interleaved
    char* sl  = (char*)(Wt4 + 512 * 256);
    size_t fixed = (size_t)(sl - base);

    // per-elem: R0 512B + R1 8192B + R2 4096B + ssq 48B = 12848 B
    int Bs = B;
    while (Bs > 512 && fixed + (size_t)Bs * 12848 > ws_size) Bs >>= 1;
    int nslice = B / Bs;
    int M = Bs * 4;

    bf16* R0 = (bf16*)sl;                       // xb FT [M,64]
    bf16* R1 = R0 + (size_t)Bs * 256;           // h1 FT [M,1024]; then h3_un FT [M,256]
    bf16* R2 = R1 + (size_t)Bs * 4096;          // h2_un FT [M,512]; then h4_un FT [M,256]
    float* ssqb = (float*)(R2 + (size_t)Bs * 2048);   // 3*M floats

    hipLaunchKernelGGL(k_setup, dim3(1), dim3(64), 0, stream, ei, gmat);
    hipLaunchKernelGGL(wtransF, dim3((1024 * 64 + 255) / 256), dim3(256), 0, stream,
                       W1, 64, 1024, Wt1);
    hipLaunchKernelGGL(wtransI, dim3((1024 * 1024 + 255) / 256), dim3(256), 0, stream,
                       Wl2, Wr2, 1024, 512, Wt2);
    hipLaunchKernelGGL(wtransI, dim3((512 * 512 + 255) / 256), dim3(256), 0, stream,
                       Wl3, Wr3, 512, 256, Wt3);
    hipLaunchKernelGGL(wtransI, dim3((512 * 256 + 255) / 256), dim3(256), 0, stream,
                       Wl4, Wr4, 256, 256, Wt4);

    for (int s = 0; s < nslice; s++) {
        const float* xs = x + (size_t)s * Bs * 256;
        hipLaunchKernelGGL(k_zero, dim3((3 * M / 4 + 255) / 256), dim3(256), 0, stream,
                           (float4*)ssqb, 3 * M / 4);
        hipLaunchKernelGGL(cast_x, dim3(Bs / 8), dim3(256), 0, stream,
                           (const float4*)xs, (bf16x8*)R0);
        // L1 GCN: h1 = relu(mix(x@W1) + b1)   [mode 1]  N=1024, K=64
        hipLaunchKernelGGL(gemm_mfma, dim3(4, M / 256), dim3(512), 0, stream,
                           R0, 64, Wt1, b1, R1, 1024, 1, gmat, (float*)nullptr);
        // L2 SAGE: h2_un (F=512) + ssq  [mode 2]  N=1024, K=1024
        hipLaunchKernelGGL(gemm_mfma, dim3(4, M / 256), dim3(512), 0, stream,
                           R1, 1024, Wt2, bl2, R2, 1024, 2, gmat + 16, ssqb);
        hipLaunchKernelGGL(norm_apply, dim3(M / 4), dim3(256), 0, stream,
                           (bf16x8*)R2, ssqb, 5);          // F=512 -> T=32 -> tsh=5
        // L3 SAGE: h3_un (F=256) into R1   N=512, K=512
        hipLaunchKernelGGL(gemm_mfma, dim3(2, M / 256), dim3(512), 0, stream,
                           R2, 512, Wt3, bl3, R1, 512, 2, gmat + 16, ssqb + M);
        hipLaunchKernelGGL(norm_apply, dim3(M / 8), dim3(256), 0, stream,
                           (bf16x8*)R1, ssqb + M, 4);      // F=256 -> T=16 -> tsh=4
        // L4 SAGE: h4_un (F=256) into R2   N=512, K=256
        hipLaunchKernelGGL(gemm_mfma, dim3(2, M / 256), dim3(512), 0, stream,
                           R1, 256, Wt4, bl4, R2, 512, 2, gmat + 16, ssqb + 2 * M);
        // FC + softmax with fused h4 norm+ReLU (FT input)
        hipLaunchKernelGGL(fc_softmax, dim3(Bs / 4), dim3(256), 0, stream,
                           (const bf16x8*)R2, ssqb + 2 * M, Wfc, bfc,
                           out + (size_t)s * Bs * 10);
    }
}